// Round 5
// baseline (506.547 us; speedup 1.0000x reference)
//
#include <hip/hip_runtime.h>
#include <hip/hip_bf16.h>
#include <stdint.h>
#include <math.h>

#define T_TOK 8192
#define HID   2048
#define NH    16
#define NKV   8
#define HD    128
#define LSEQ  1024
#define BATCH 8
#define QKV_N 4096
#define KDIM  2048
#define NT32  64          // K-tiles of 32 over KDIM=2048
#define SCALE 0.08838834764831845f   // 1/sqrt(128)

typedef __hip_bfloat16 bf16;
typedef __bf16 bf16x8 __attribute__((ext_vector_type(8)));
typedef float  f32x4  __attribute__((ext_vector_type(4)));

typedef const void __attribute__((address_space(1)))* gas_ptr;
typedef void       __attribute__((address_space(3)))* las_ptr;

__device__ __forceinline__ float b2f(bf16 x) { return __bfloat162float(x); }
__device__ __forceinline__ bf16  f2b(float x) { return __float2bfloat16(x); }
__device__ __forceinline__ unsigned short f2u(float x) {
    union { bf16 b; unsigned short u; } c; c.b = __float2bfloat16(x); return c.u;
}

__device__ __forceinline__ bf16x8 ld16(const void* p) {
    union { uint4 u; bf16x8 v; } c;
    c.u = *reinterpret_cast<const uint4*>(p);
    return c.v;
}

// async 16B/lane global->LDS. lds must be wave-uniform base; HW adds lane*16.
__device__ __forceinline__ void cp16(void* lds, const void* g) {
    __builtin_amdgcn_global_load_lds((gas_ptr)g, (las_ptr)lds, 16, 0, 0);
}

#define BARX() do { asm volatile("" ::: "memory"); \
                    __builtin_amdgcn_s_barrier();  \
                    asm volatile("" ::: "memory"); } while (0)

// ---------------- fp32 -> bf16 convert (grid-stride, vectorized) -------------
__global__ __launch_bounds__(256) void k_f2b(const float* __restrict__ in,
                                             bf16* __restrict__ out, int n) {
    int i = blockIdx.x * blockDim.x + threadIdx.x;
    int stride = gridDim.x * blockDim.x;
    const float4* in4 = (const float4*)in;
    ushort4* out4 = (ushort4*)out;
    int n4 = n >> 2;
    for (int j = i; j < n4; j += stride) {
        float4 v = in4[j];
        ushort4 o;
        o.x = f2u(v.x); o.y = f2u(v.y); o.z = f2u(v.z); o.w = f2u(v.w);
        out4[j] = o;
    }
}

// ---------------- modality map ----------------------------------------------
__global__ __launch_bounds__(256) void k_mod(const int* __restrict__ und,
                                             const int* __restrict__ gen,
                                             int* __restrict__ mod, int n) {
    int i = blockIdx.x * blockDim.x + threadIdx.x;
    if (i < n) { mod[und[i]] = 0; mod[gen[i]] = 1; }
}

// ---------------- routed GEMM: 256x256 tile, BK=32, 4 LDS buffers, 8-phase ---
// C[idx[row]][col] = sum_k A[idx[row]][k] * Bw[col][k]  (+ bias, EPI==0)
// LDS 128KB: 4 buffers x {A 256x32, B 256x32} bf16 (32KB each), linear layout
// for global_load_lds; swizzle: 16B-chunk position = chunk ^ (row&3), applied
// on global source AND ds_read (rule #21). Pipeline: stage tiles 0..2; per
// K-tile t: ph0 {read B n0-3 + A m0-3, stage A(t+3), bar, 16 MFMA, bar},
// ph1 {read A m4-7, stage B(t+3), vmcnt(8), bar, 16 MFMA, bar}. Two tiles
// (8 loads/wave) stay in flight across barriers; vmcnt never 0 mid-loop.
template<int EPI>
__global__ __launch_bounds__(512)
void k_gemm8p(const bf16* __restrict__ A,
              const bf16* __restrict__ Bw_u, const bf16* __restrict__ Bw_g,
              const int* __restrict__ und, const int* __restrict__ gen,
              const float* __restrict__ bq_u, const float* __restrict__ bk_u,
              const float* __restrict__ bv_u,
              const float* __restrict__ bq_g, const float* __restrict__ bk_g,
              const float* __restrict__ bv_g,
              bf16* __restrict__ outB, float* __restrict__ outF) {
    extern __shared__ char smem[];

    int modg = blockIdx.y;
    const bf16* Bw = modg ? Bw_g : Bw_u;
    const int* idx = modg ? gen : und;
    const float* bq = modg ? bq_g : bq_u;
    const float* bk = modg ? bk_g : bk_u;
    const float* bv = modg ? bv_g : bv_u;

    // XCD swizzle (gridDim.x % 8 == 0); tm fastest within XCD chunk
    int gx = gridDim.x;
    int bid = blockIdx.x;
    int sw = (bid & 7) * (gx >> 3) + (bid >> 3);
    int tn = sw >> 4, tm = sw & 15;

    int tid = threadIdx.x;
    int w = tid >> 6, lane = tid & 63;
    int l16 = lane & 15, l4 = lane >> 4;
    int wm = w >> 2, wn = w & 3;   // 2M x 4N waves -> per-wave C = 128 x 64

    // ---- staging source pointers: unit 0 = A-tile, unit 1 = B-tile (16KB ea)
    // wave-load j covers LDS rows (j*8+w)*16 + (lane>>2), chunk pos lane&3;
    // content chunk = pos ^ (row&3)  ->  source chunk = (lane&3)^((lane>>2)&3)
    int chunk = (lane & 3) ^ ((lane >> 2) & 3);
    const bf16* pS[2][2];
#pragma unroll
    for (int j = 0; j < 2; ++j) {
        int R = (j * 8 + w) * 16 + (lane >> 2);   // 0..255
        pS[0][j] = A + (size_t)idx[tm * 256 + R] * KDIM + chunk * 8;
        pS[1][j] = Bw + (size_t)(tn * 256 + R) * KDIM + chunk * 8;
    }

    auto STAGE = [&](int t, int u) {
        char* base = smem + (t & 3) * 32768 + u * 16384 + w * 1024;
        cp16(base,        pS[u][0] + t * 32);
        cp16(base + 8192, pS[u][1] + t * 32);
    };

    f32x4 acc[8][4];
#pragma unroll
    for (int m = 0; m < 8; ++m)
#pragma unroll
        for (int n = 0; n < 4; ++n) acc[m][n] = {0.f, 0.f, 0.f, 0.f};

    // prologue: 3 tiles in flight
    STAGE(0, 0); STAGE(0, 1);
    STAGE(1, 0); STAGE(1, 1);
    STAGE(2, 0); STAGE(2, 1);
    asm volatile("s_waitcnt vmcnt(8)" ::: "memory");   // tile 0 resident
    BARX();

    uint32_t aRow = (uint32_t)(wm * 128 + l16) * 64;   // + m*1024
    uint32_t bRow = 16384u + (uint32_t)(wn * 64 + l16) * 64;  // + n*1024
    uint32_t cByte = (uint32_t)((l4 ^ (l16 & 3)) << 4);

#pragma unroll 1
    for (int t = 0; t < NT32; ++t) {
        const char* buf = smem + (t & 3) * 32768;
        // ---------------- phase 0: B all + A m0-3; stage A(t+3)
        bf16x8 bf_[4], af[4];
#pragma unroll
        for (int n = 0; n < 4; ++n) bf_[n] = ld16(buf + bRow + n * 1024 + cByte);
#pragma unroll
        for (int m = 0; m < 4; ++m) af[m] = ld16(buf + aRow + m * 1024 + cByte);
        if (t + 3 < NT32) STAGE(t + 3, 0);
        BARX();
        __builtin_amdgcn_s_setprio(1);
#pragma unroll
        for (int m = 0; m < 4; ++m)
#pragma unroll
            for (int n = 0; n < 4; ++n)
                acc[m][n] = __builtin_amdgcn_mfma_f32_16x16x32_bf16(af[m], bf_[n], acc[m][n], 0, 0, 0);
        __builtin_amdgcn_s_setprio(0);
        BARX();
        // ---------------- phase 1: A m4-7; stage B(t+3); counted vmcnt
        bf16x8 af2[4];
#pragma unroll
        for (int m = 0; m < 4; ++m) af2[m] = ld16(buf + aRow + (m + 4) * 1024 + cByte);
        if (t + 3 < NT32) {
            STAGE(t + 3, 1);
            asm volatile("s_waitcnt vmcnt(8)" ::: "memory");   // t+1 resident
        } else if (t + 2 < NT32) {
            asm volatile("s_waitcnt vmcnt(4)" ::: "memory");
        } else {
            asm volatile("s_waitcnt vmcnt(0)" ::: "memory");
        }
        BARX();
        __builtin_amdgcn_s_setprio(1);
#pragma unroll
        for (int m = 0; m < 4; ++m)
#pragma unroll
            for (int n = 0; n < 4; ++n)
                acc[m + 4][n] = __builtin_amdgcn_mfma_f32_16x16x32_bf16(af2[m], bf_[n], acc[m + 4][n], 0, 0, 0);
        __builtin_amdgcn_s_setprio(0);
        BARX();
    }

    int rowbase = tm * 256 + wm * 128;
    int colbase = tn * 256 + wn * 64;
#pragma unroll
    for (int m = 0; m < 8; ++m) {
#pragma unroll
        for (int r = 0; r < 4; ++r) {
            int row = rowbase + m * 16 + l4 * 4 + r;
            int token = idx[row];
#pragma unroll
            for (int n = 0; n < 4; ++n) {
                int col = colbase + n * 16 + l16;
                float v = acc[m][n][r];
                if (EPI == 0) {
                    float bias = (col < 2048) ? bq[col]
                               : (col < 3072) ? bk[col - 2048] : bv[col - 3072];
                    outB[(size_t)token * QKV_N + col] = f2b(v + bias);
                } else {
                    outF[(size_t)token * HID + col] = v;
                }
            }
        }
    }
}

// ---------------- per-head RMSNorm + RoPE (Q,K only) -------------------------
__global__ __launch_bounds__(256)
void k_normrope(const bf16* __restrict__ qkv,
                const float* __restrict__ cosT, const float* __restrict__ sinT,
                const int* __restrict__ mod,
                const float* __restrict__ qn_u, const float* __restrict__ qn_g,
                const float* __restrict__ kn_u, const float* __restrict__ kn_g,
                bf16* __restrict__ Qo, bf16* __restrict__ Ko) {
    int t = blockIdx.x;
    int tid = threadIdx.x;
    int w = tid >> 6, lane = tid & 63;
    int m = mod[t];
    int b = t >> 10, pos = t & 1023;
    const bf16* row = qkv + (size_t)t * QKV_N;
    int d0 = 2 * lane, d1 = 2 * lane + 1;
    float c0 = cosT[(size_t)t * HD + d0], c1 = cosT[(size_t)t * HD + d1];
    float s0 = sinT[(size_t)t * HD + d0], s1 = sinT[(size_t)t * HD + d1];
    float sgn = (lane < 32) ? -1.f : 1.f;
    const float* qw = m ? qn_g : qn_u;
    const float* kw = m ? kn_g : kn_u;

    for (int u = w; u < 24; u += 4) {
        float v0 = b2f(row[u * HD + d0]);
        float v1 = b2f(row[u * HD + d1]);
        float ss = v0 * v0 + v1 * v1;
#pragma unroll
        for (int msk = 1; msk < 64; msk <<= 1) ss += __shfl_xor(ss, msk);
        float rs = rsqrtf(ss * (1.0f / HD) + 1e-6f);
        const float* wsc = (u < 16) ? qw : kw;
        float n0 = v0 * rs * wsc[d0], n1 = v1 * rs * wsc[d1];
        float o0 = __shfl_xor(n0, 32), o1 = __shfl_xor(n1, 32);
        float r0 = n0 * c0 + sgn * o0 * s0;
        float r1 = n1 * c1 + sgn * o1 * s1;
        if (u < 16) {
            size_t o = ((size_t)(b * NH + u) * LSEQ + pos) * HD;
            Qo[o + d0] = f2b(r0); Qo[o + d1] = f2b(r1);
        } else {
            size_t o = ((size_t)(b * NKV + (u - 16)) * LSEQ + pos) * HD;
            Ko[o + d0] = f2b(r0); Ko[o + d1] = f2b(r1);
        }
    }
}

// ---------------- V transpose: qkv[t][3072+kv*128+d] -> Vt[b,kv][d][pos] -----
__global__ __launch_bounds__(256)
void k_vt(const bf16* __restrict__ qkv, bf16* __restrict__ Vt) {
    __shared__ bf16 lds[64][72];
    int bk = blockIdx.x;
    int b = bk >> 3, kv = bk & 7;
    int pos0 = blockIdx.y * 64;
    int d0 = blockIdx.z * 64;
    int tid = threadIdx.x;

#pragma unroll
    for (int it = 0; it < 2; ++it) {
        int c = tid + it * 256;
        int row = c >> 3, col8 = (c & 7) * 8;
        const bf16* src = qkv + (size_t)(b * LSEQ + pos0 + row) * QKV_N
                        + 3072 + kv * HD + d0 + col8;
        *reinterpret_cast<uint4*>(&lds[row][col8]) = *reinterpret_cast<const uint4*>(src);
    }
    __syncthreads();

#pragma unroll
    for (int it = 0; it < 2; ++it) {
        int c = tid + it * 256;
        int drow = c & 63, pos8 = (c >> 6) * 8;
        union { unsigned short s[8]; uint4 u; } g;
#pragma unroll
        for (int j = 0; j < 8; ++j)
            g.s[j] = *reinterpret_cast<const unsigned short*>(&lds[pos8 + j][drow]);
        bf16* dst = Vt + ((size_t)bk * HD + d0 + drow) * LSEQ + pos0 + pos8;
        *reinterpret_cast<uint4*>(dst) = g.u;
    }
}

// ---------------- causal GQA flash attention (balanced, 32 q-rows/wave) ------
__global__ __launch_bounds__(256)
void k_attn(const bf16* __restrict__ Q, const bf16* __restrict__ K,
            const bf16* __restrict__ Vt, bf16* __restrict__ O) {
    int bid = blockIdx.x;
    int p = bid & 3;
    int h = (bid >> 2) & 15;
    int b = bid >> 6;
    int tid = threadIdx.x;
    int w = tid >> 6, lane = tid & 63;
    int l16 = lane & 15, l4 = lane >> 4;
    int j = p * 4 + w;

    const bf16* qhb = Q + (size_t)(b * NH + h) * LSEQ * HD;
    int kv = h >> 1;
    const bf16* kb = K + (size_t)(b * NKV + kv) * LSEQ * HD;
    const bf16* vtb = Vt + (size_t)(b * NKV + kv) * HD * LSEQ;

    __shared__ bf16 Pl[4][32][72];

    f32x4 zero = {0.f, 0.f, 0.f, 0.f};

#pragma unroll 1
    for (int half = 0; half < 2; ++half) {
        int rowblk = half ? (31 - j) : j;
        int q0 = rowblk * 32;
        int kend = q0 + 32;

        bf16x8 qf[2][4];
#pragma unroll
        for (int rf = 0; rf < 2; ++rf)
#pragma unroll
            for (int c = 0; c < 4; ++c)
                qf[rf][c] = ld16(qhb + (size_t)(q0 + rf * 16 + l16) * HD + c * 32 + l4 * 8);

        f32x4 oacc[2][8];
#pragma unroll
        for (int rf = 0; rf < 2; ++rf)
#pragma unroll
            for (int d = 0; d < 8; ++d) oacc[rf][d] = zero;
        float mr[2][4], lr[2][4];
#pragma unroll
        for (int rf = 0; rf < 2; ++rf)
#pragma unroll
            for (int r = 0; r < 4; ++r) { mr[rf][r] = -INFINITY; lr[rf][r] = 0.f; }

        for (int kt = 0; kt < kend; kt += 64) {
            f32x4 s[2][4];
#pragma unroll
            for (int rf = 0; rf < 2; ++rf)
#pragma unroll
                for (int kf = 0; kf < 4; ++kf) s[rf][kf] = zero;
#pragma unroll
            for (int c = 0; c < 4; ++c) {
                bf16x8 kf4[4];
#pragma unroll
                for (int kf = 0; kf < 4; ++kf)
                    kf4[kf] = ld16(kb + (size_t)(kt + kf * 16 + l16) * HD + c * 32 + l4 * 8);
#pragma unroll
                for (int rf = 0; rf < 2; ++rf)
#pragma unroll
                    for (int kf = 0; kf < 4; ++kf)
                        s[rf][kf] = __builtin_amdgcn_mfma_f32_16x16x32_bf16(qf[rf][c], kf4[kf], s[rf][kf], 0, 0, 0);
            }
#pragma unroll
            for (int rf = 0; rf < 2; ++rf) {
#pragma unroll
                for (int r = 0; r < 4; ++r) {
                    int qrow = q0 + rf * 16 + l4 * 4 + r;
                    float sc[4];
                    float rm = -1e30f;
#pragma unroll
                    for (int kf = 0; kf < 4; ++kf) {
                        int key = kt + kf * 16 + l16;
                        sc[kf] = (key <= qrow) ? s[rf][kf][r] * SCALE : -1e30f;
                        rm = fmaxf(rm, sc[kf]);
                    }
#pragma unroll
                    for (int msk = 1; msk < 16; msk <<= 1) rm = fmaxf(rm, __shfl_xor(rm, msk));
                    float mn = fmaxf(mr[rf][r], rm);
                    float corr = __expf(mr[rf][r] - mn);
                    mr[rf][r] = mn;
                    float rsum = 0.f;
#pragma unroll
                    for (int kf = 0; kf < 4; ++kf) {
                        float pv = __expf(sc[kf] - mn);
                        rsum += pv;
                        Pl[w][rf * 16 + l4 * 4 + r][kf * 16 + l16] = f2b(pv);
                    }
#pragma unroll
                    for (int msk = 1; msk < 16; msk <<= 1) rsum += __shfl_xor(rsum, msk);
                    lr[rf][r] = lr[rf][r] * corr + rsum;
#pragma unroll
                    for (int d = 0; d < 8; ++d) oacc[rf][d][r] *= corr;
                }
            }
            bf16x8 pf[2][2];
#pragma unroll
            for (int rf = 0; rf < 2; ++rf)
#pragma unroll
                for (int ks = 0; ks < 2; ++ks)
                    pf[rf][ks] = ld16(&Pl[w][rf * 16 + l16][ks * 32 + l4 * 8]);
#pragma unroll
            for (int dt = 0; dt < 8; ++dt) {
#pragma unroll
                for (int ks = 0; ks < 2; ++ks) {
                    bf16x8 vfr = ld16(vtb + (size_t)(dt * 16 + l16) * LSEQ + kt + ks * 32 + l4 * 8);
#pragma unroll
                    for (int rf = 0; rf < 2; ++rf)
                        oacc[rf][dt] = __builtin_amdgcn_mfma_f32_16x16x32_bf16(pf[rf][ks], vfr, oacc[rf][dt], 0, 0, 0);
                }
            }
        }

#pragma unroll
        for (int rf = 0; rf < 2; ++rf)
#pragma unroll
            for (int r = 0; r < 4; ++r) lr[rf][r] = 1.0f / lr[rf][r];
        int trow = b * LSEQ + q0;
#pragma unroll
        for (int rf = 0; rf < 2; ++rf)
#pragma unroll
            for (int dt = 0; dt < 8; ++dt)
#pragma unroll
                for (int r = 0; r < 4; ++r) {
                    int t = trow + rf * 16 + l4 * 4 + r;
                    O[(size_t)t * HID + h * HD + dt * 16 + l16] = f2b(oacc[rf][dt][r] * lr[rf][r]);
                }
    }
}

// ---------------- launch -----------------------------------------------------
extern "C" void kernel_launch(void* const* d_in, const int* in_sizes, int n_in,
                              void* d_out, int out_size, void* d_ws, size_t ws_size,
                              hipStream_t stream) {
    const float* x    = (const float*)d_in[0];
    const float* cosT = (const float*)d_in[1];
    const float* sinT = (const float*)d_in[2];
    const int* und = (const int*)d_in[4];
    const int* gen = (const int*)d_in[5];
    const float* Wq_u = (const float*)d_in[6];
    const float* bq_u = (const float*)d_in[7];
    const float* Wk_u = (const float*)d_in[8];
    const float* bk_u = (const float*)d_in[9];
    const float* Wv_u = (const float*)d_in[10];
    const float* bv_u = (const float*)d_in[11];
    const float* Wo_u = (const float*)d_in[12];
    const float* Wq_g = (const float*)d_in[13];
    const float* bq_g = (const float*)d_in[14];
    const float* Wk_g = (const float*)d_in[15];
    const float* bk_g = (const float*)d_in[16];
    const float* Wv_g = (const float*)d_in[17];
    const float* bv_g = (const float*)d_in[18];
    const float* Wo_g = (const float*)d_in[19];
    const float* qn_u = (const float*)d_in[20];
    const float* kn_u = (const float*)d_in[21];
    const float* qn_g = (const float*)d_in[22];
    const float* kn_g = (const float*)d_in[23];
    float* out = (float*)d_out;

    char* ws = (char*)d_ws;
    size_t off = 0;
    auto alloc = [&](size_t bytes) -> void* {
        void* p = ws + off;
        off += (bytes + 255) & ~(size_t)255;
        return p;
    };
    bf16* xb      = (bf16*)alloc((size_t)T_TOK * HID * 2);
    bf16* Wqkv_u  = (bf16*)alloc((size_t)QKV_N * KDIM * 2);
    bf16* Wqkv_g  = (bf16*)alloc((size_t)QKV_N * KDIM * 2);
    bf16* Wob_u   = (bf16*)alloc((size_t)HID * HID * 2);
    bf16* Wob_g   = (bf16*)alloc((size_t)HID * HID * 2);
    int*  mod     = (int*)alloc((size_t)T_TOK * 4);
    bf16* qkv     = (bf16*)alloc((size_t)T_TOK * QKV_N * 2);
    bf16* Qa      = (bf16*)alloc((size_t)BATCH * NH  * LSEQ * HD * 2);
    bf16* Ka      = (bf16*)alloc((size_t)BATCH * NKV * LSEQ * HD * 2);
    bf16* Vt      = (bf16*)alloc((size_t)BATCH * NKV * HD * LSEQ * 2);
    bf16* Ob      = (bf16*)alloc((size_t)T_TOK * HID * 2);
    (void)ws_size; (void)in_sizes; (void)n_in; (void)out_size;

    // allow 128KB dynamic LDS for the GEMM kernels (idempotent, capture-safe)
    (void)hipFuncSetAttribute((const void*)k_gemm8p<0>,
                              hipFuncAttributeMaxDynamicSharedMemorySize, 131072);
    (void)hipFuncSetAttribute((const void*)k_gemm8p<1>,
                              hipFuncAttributeMaxDynamicSharedMemorySize, 131072);

    // converts
    k_f2b<<<1024, 256, 0, stream>>>(x, xb, T_TOK * HID);
    k_f2b<<<1024, 256, 0, stream>>>(Wq_u, Wqkv_u,               2048 * 2048);
    k_f2b<<<1024, 256, 0, stream>>>(Wk_u, Wqkv_u + 2048 * 2048, 1024 * 2048);
    k_f2b<<<1024, 256, 0, stream>>>(Wv_u, Wqkv_u + 3072 * 2048, 1024 * 2048);
    k_f2b<<<1024, 256, 0, stream>>>(Wq_g, Wqkv_g,               2048 * 2048);
    k_f2b<<<1024, 256, 0, stream>>>(Wk_g, Wqkv_g + 2048 * 2048, 1024 * 2048);
    k_f2b<<<1024, 256, 0, stream>>>(Wv_g, Wqkv_g + 3072 * 2048, 1024 * 2048);
    k_f2b<<<1024, 256, 0, stream>>>(Wo_u, Wob_u, 2048 * 2048);
    k_f2b<<<1024, 256, 0, stream>>>(Wo_g, Wob_g, 2048 * 2048);
    k_mod<<<16, 256, 0, stream>>>(und, gen, mod, T_TOK / 2);

    // routed QKV projections (M=4096, N=4096, K=2048; both modalities)
    k_gemm8p<0><<<dim3(16 * 16, 2), 512, 131072, stream>>>(
        xb, Wqkv_u, Wqkv_g, und, gen, bq_u, bk_u, bv_u, bq_g, bk_g, bv_g,
        qkv, nullptr);

    // RMS + RoPE (Q,K) and V transpose
    k_normrope<<<T_TOK, 256, 0, stream>>>(qkv, cosT, sinT, mod,
                                          qn_u, qn_g, kn_u, kn_g, Qa, Ka);
    k_vt<<<dim3(BATCH * NKV, LSEQ / 64, HD / 64), 256, 0, stream>>>(qkv, Vt);

    // causal GQA attention (balanced pairing: 512 uniform blocks)
    k_attn<<<BATCH * NH * 4, 256, 0, stream>>>(Qa, Ka, Vt, Ob);

    // routed output projections (M=4096, N=2048, K=2048; both modalities)
    k_gemm8p<1><<<dim3(8 * 16, 2), 512, 131072, stream>>>(
        Ob, Wob_u, Wob_g, und, gen, nullptr, nullptr, nullptr,
        nullptr, nullptr, nullptr, nullptr, out);
}

// Round 6
// 503.346 us; speedup vs baseline: 1.0064x; 1.0064x over previous
//
#include <hip/hip_runtime.h>
#include <hip/hip_bf16.h>
#include <stdint.h>
#include <math.h>

#define T_TOK 8192
#define HID   2048
#define NH    16
#define NKV   8
#define HD    128
#define LSEQ  1024
#define BATCH 8
#define QKV_N 4096
#define KDIM  2048
#define NT32  64          // K-tiles of 32 over KDIM=2048
#define SCALE 0.08838834764831845f   // 1/sqrt(128)

typedef __hip_bfloat16 bf16;
typedef __bf16 bf16x8 __attribute__((ext_vector_type(8)));
typedef float  f32x4  __attribute__((ext_vector_type(4)));

typedef const void __attribute__((address_space(1)))* gas_ptr;
typedef void       __attribute__((address_space(3)))* las_ptr;

__device__ __forceinline__ float b2f(bf16 x) { return __bfloat162float(x); }
__device__ __forceinline__ bf16  f2b(float x) { return __float2bfloat16(x); }
__device__ __forceinline__ unsigned short f2u(float x) {
    union { bf16 b; unsigned short u; } c; c.b = __float2bfloat16(x); return c.u;
}

__device__ __forceinline__ bf16x8 ld16(const void* p) {
    union { uint4 u; bf16x8 v; } c;
    c.u = *reinterpret_cast<const uint4*>(p);
    return c.v;
}

// async 16B/lane global->LDS. lds must be wave-uniform base; HW adds lane*16.
__device__ __forceinline__ void cp16(void* lds, const void* g) {
    __builtin_amdgcn_global_load_lds((gas_ptr)g, (las_ptr)lds, 16, 0, 0);
}

#define BARX() do { asm volatile("" ::: "memory"); \
                    __builtin_amdgcn_s_barrier();  \
                    asm volatile("" ::: "memory"); } while (0)

// ---------------- fp32 -> bf16 convert (grid-stride, vectorized) -------------
__global__ __launch_bounds__(256) void k_f2b(const float* __restrict__ in,
                                             bf16* __restrict__ out, int n) {
    int i = blockIdx.x * blockDim.x + threadIdx.x;
    int stride = gridDim.x * blockDim.x;
    const float4* in4 = (const float4*)in;
    ushort4* out4 = (ushort4*)out;
    int n4 = n >> 2;
    for (int j = i; j < n4; j += stride) {
        float4 v = in4[j];
        ushort4 o;
        o.x = f2u(v.x); o.y = f2u(v.y); o.z = f2u(v.z); o.w = f2u(v.w);
        out4[j] = o;
    }
}

// ---------------- modality map ----------------------------------------------
__global__ __launch_bounds__(256) void k_mod(const int* __restrict__ und,
                                             const int* __restrict__ gen,
                                             int* __restrict__ mod, int n) {
    int i = blockIdx.x * blockDim.x + threadIdx.x;
    if (i < n) { mod[und[i]] = 0; mod[gen[i]] = 1; }
}

// ---------------- routed GEMM: 256x256 tile, BK=32, 4 LDS buffers, 8-phase ---
// C[idx[row]][col] = sum_k A[idx[row]][k] * Bw[col][k]  (+ bias, EPI==0)
// LDS 128KB: 4 buffers x {A 256x32, B 256x32} bf16. Swizzle (64B rows, 4x16B
// chunks): content(row,pos) = global chunk pos ^ ((row>>1)&3). Read pos =
// l4 ^ ((l16>>1)&3) -> granule (4*l16+pos)&7 covers 0..7 exactly 2x per
// 16-lane group = conflict-free (m136: 2-way is free). Source chunk for
// linear global_load_lds dest: (lane&3) ^ ((lane>>3)&3) (rule #21 both-sides).
// Pipeline: stage tiles 0..2; per K-tile t: ph0 {read B + A m0-3, stage
// A(t+3), bar, 16 MFMA, bar}, ph1 {read A m4-7, stage B(t+3), vmcnt(8),
// bar, 16 MFMA, bar}. vmcnt never 0 mid-loop (2 tiles in flight).
template<int EPI>
__global__ __launch_bounds__(512)
void k_gemm8p(const bf16* __restrict__ A,
              const bf16* __restrict__ Bw_u, const bf16* __restrict__ Bw_g,
              const int* __restrict__ und, const int* __restrict__ gen,
              const float* __restrict__ bq_u, const float* __restrict__ bk_u,
              const float* __restrict__ bv_u,
              const float* __restrict__ bq_g, const float* __restrict__ bk_g,
              const float* __restrict__ bv_g,
              bf16* __restrict__ outB, float* __restrict__ outF) {
    extern __shared__ char smem[];

    int modg = blockIdx.y;
    const bf16* Bw = modg ? Bw_g : Bw_u;
    const int* idx = modg ? gen : und;
    const float* bq = modg ? bq_g : bq_u;
    const float* bk = modg ? bk_g : bk_u;
    const float* bv = modg ? bv_g : bv_u;

    // XCD swizzle (gridDim.x % 8 == 0); tm fastest within XCD chunk
    int gx = gridDim.x;
    int bid = blockIdx.x;
    int sw = (bid & 7) * (gx >> 3) + (bid >> 3);
    int tn = sw >> 4, tm = sw & 15;

    int tid = threadIdx.x;
    int w = tid >> 6, lane = tid & 63;
    int l16 = lane & 15, l4 = lane >> 4;
    int wm = w >> 2, wn = w & 3;   // 2M x 4N waves -> per-wave C = 128 x 64

    // ---- staging source pointers: unit 0 = A-tile, unit 1 = B-tile (16KB ea)
    // wave-load j covers LDS rows (j*8+w)*16 + (lane>>2), pos chunk lane&3;
    // content chunk = pos ^ ((row>>1)&3) -> source chunk = (lane&3)^((lane>>3)&3)
    int chunk = (lane & 3) ^ ((lane >> 3) & 3);
    const bf16* pS[2][2];
#pragma unroll
    for (int j = 0; j < 2; ++j) {
        int R = (j * 8 + w) * 16 + (lane >> 2);   // 0..255
        pS[0][j] = A + (size_t)idx[tm * 256 + R] * KDIM + chunk * 8;
        pS[1][j] = Bw + (size_t)(tn * 256 + R) * KDIM + chunk * 8;
    }

    auto STAGE = [&](int t, int u) {
        char* base = smem + (t & 3) * 32768 + u * 16384 + w * 1024;
        cp16(base,        pS[u][0] + t * 32);
        cp16(base + 8192, pS[u][1] + t * 32);
    };

    f32x4 acc[8][4];
#pragma unroll
    for (int m = 0; m < 8; ++m)
#pragma unroll
        for (int n = 0; n < 4; ++n) acc[m][n] = {0.f, 0.f, 0.f, 0.f};

    // prologue: 3 tiles in flight
    STAGE(0, 0); STAGE(0, 1);
    STAGE(1, 0); STAGE(1, 1);
    STAGE(2, 0); STAGE(2, 1);
    asm volatile("s_waitcnt vmcnt(8)" ::: "memory");   // tile 0 resident
    BARX();

    uint32_t aRow = (uint32_t)(wm * 128 + l16) * 64;          // + m*1024
    uint32_t bRow = 16384u + (uint32_t)(wn * 64 + l16) * 64;  // + n*1024
    uint32_t cByte = (uint32_t)((l4 ^ ((l16 >> 1) & 3)) << 4);  // conflict-free

#pragma unroll 1
    for (int t = 0; t < NT32; ++t) {
        const char* buf = smem + (t & 3) * 32768;
        // ---------------- phase 0: B all + A m0-3; stage A(t+3)
        bf16x8 bf_[4], af[4];
#pragma unroll
        for (int n = 0; n < 4; ++n) bf_[n] = ld16(buf + bRow + n * 1024 + cByte);
#pragma unroll
        for (int m = 0; m < 4; ++m) af[m] = ld16(buf + aRow + m * 1024 + cByte);
        if (t + 3 < NT32) STAGE(t + 3, 0);
        BARX();
        __builtin_amdgcn_s_setprio(1);
#pragma unroll
        for (int m = 0; m < 4; ++m)
#pragma unroll
            for (int n = 0; n < 4; ++n)
                acc[m][n] = __builtin_amdgcn_mfma_f32_16x16x32_bf16(af[m], bf_[n], acc[m][n], 0, 0, 0);
        __builtin_amdgcn_s_setprio(0);
        BARX();
        // ---------------- phase 1: A m4-7; stage B(t+3); counted vmcnt
        bf16x8 af2[4];
#pragma unroll
        for (int m = 0; m < 4; ++m) af2[m] = ld16(buf + aRow + (m + 4) * 1024 + cByte);
        if (t + 3 < NT32) {
            STAGE(t + 3, 1);
            asm volatile("s_waitcnt vmcnt(8)" ::: "memory");   // t+1 resident
        } else if (t + 2 < NT32) {
            asm volatile("s_waitcnt vmcnt(4)" ::: "memory");
        } else {
            asm volatile("s_waitcnt vmcnt(0)" ::: "memory");
        }
        BARX();
        __builtin_amdgcn_s_setprio(1);
#pragma unroll
        for (int m = 0; m < 4; ++m)
#pragma unroll
            for (int n = 0; n < 4; ++n)
                acc[m + 4][n] = __builtin_amdgcn_mfma_f32_16x16x32_bf16(af2[m], bf_[n], acc[m + 4][n], 0, 0, 0);
        __builtin_amdgcn_s_setprio(0);
        BARX();
    }

    int rowbase = tm * 256 + wm * 128;
    int colbase = tn * 256 + wn * 64;
#pragma unroll
    for (int m = 0; m < 8; ++m) {
#pragma unroll
        for (int r = 0; r < 4; ++r) {
            int row = rowbase + m * 16 + l4 * 4 + r;
            int token = idx[row];
#pragma unroll
            for (int n = 0; n < 4; ++n) {
                int col = colbase + n * 16 + l16;
                float v = acc[m][n][r];
                if (EPI == 0) {
                    float bias = (col < 2048) ? bq[col]
                               : (col < 3072) ? bk[col - 2048] : bv[col - 3072];
                    outB[(size_t)token * QKV_N + col] = f2b(v + bias);
                } else {
                    outF[(size_t)token * HID + col] = v;
                }
            }
        }
    }
}

// ---------------- per-head RMSNorm + RoPE (Q,K only) -------------------------
__global__ __launch_bounds__(256)
void k_normrope(const bf16* __restrict__ qkv,
                const float* __restrict__ cosT, const float* __restrict__ sinT,
                const int* __restrict__ mod,
                const float* __restrict__ qn_u, const float* __restrict__ qn_g,
                const float* __restrict__ kn_u, const float* __restrict__ kn_g,
                bf16* __restrict__ Qo, bf16* __restrict__ Ko) {
    int t = blockIdx.x;
    int tid = threadIdx.x;
    int w = tid >> 6, lane = tid & 63;
    int m = mod[t];
    int b = t >> 10, pos = t & 1023;
    const bf16* row = qkv + (size_t)t * QKV_N;
    int d0 = 2 * lane, d1 = 2 * lane + 1;
    float c0 = cosT[(size_t)t * HD + d0], c1 = cosT[(size_t)t * HD + d1];
    float s0 = sinT[(size_t)t * HD + d0], s1 = sinT[(size_t)t * HD + d1];
    float sgn = (lane < 32) ? -1.f : 1.f;
    const float* qw = m ? qn_g : qn_u;
    const float* kw = m ? kn_g : kn_u;

    for (int u = w; u < 24; u += 4) {
        float v0 = b2f(row[u * HD + d0]);
        float v1 = b2f(row[u * HD + d1]);
        float ss = v0 * v0 + v1 * v1;
#pragma unroll
        for (int msk = 1; msk < 64; msk <<= 1) ss += __shfl_xor(ss, msk);
        float rs = rsqrtf(ss * (1.0f / HD) + 1e-6f);
        const float* wsc = (u < 16) ? qw : kw;
        float n0 = v0 * rs * wsc[d0], n1 = v1 * rs * wsc[d1];
        float o0 = __shfl_xor(n0, 32), o1 = __shfl_xor(n1, 32);
        float r0 = n0 * c0 + sgn * o0 * s0;
        float r1 = n1 * c1 + sgn * o1 * s1;
        if (u < 16) {
            size_t o = ((size_t)(b * NH + u) * LSEQ + pos) * HD;
            Qo[o + d0] = f2b(r0); Qo[o + d1] = f2b(r1);
        } else {
            size_t o = ((size_t)(b * NKV + (u - 16)) * LSEQ + pos) * HD;
            Ko[o + d0] = f2b(r0); Ko[o + d1] = f2b(r1);
        }
    }
}

// ---------------- V transpose: qkv[t][3072+kv*128+d] -> Vt[b,kv][d][pos] -----
__global__ __launch_bounds__(256)
void k_vt(const bf16* __restrict__ qkv, bf16* __restrict__ Vt) {
    __shared__ bf16 lds[64][72];
    int bk = blockIdx.x;
    int b = bk >> 3, kv = bk & 7;
    int pos0 = blockIdx.y * 64;
    int d0 = blockIdx.z * 64;
    int tid = threadIdx.x;

#pragma unroll
    for (int it = 0; it < 2; ++it) {
        int c = tid + it * 256;
        int row = c >> 3, col8 = (c & 7) * 8;
        const bf16* src = qkv + (size_t)(b * LSEQ + pos0 + row) * QKV_N
                        + 3072 + kv * HD + d0 + col8;
        *reinterpret_cast<uint4*>(&lds[row][col8]) = *reinterpret_cast<const uint4*>(src);
    }
    __syncthreads();

#pragma unroll
    for (int it = 0; it < 2; ++it) {
        int c = tid + it * 256;
        int drow = c & 63, pos8 = (c >> 6) * 8;
        union { unsigned short s[8]; uint4 u; } g;
#pragma unroll
        for (int j = 0; j < 8; ++j)
            g.s[j] = *reinterpret_cast<const unsigned short*>(&lds[pos8 + j][drow]);
        bf16* dst = Vt + ((size_t)bk * HD + d0 + drow) * LSEQ + pos0 + pos8;
        *reinterpret_cast<uint4*>(dst) = g.u;
    }
}

// ---------------- causal GQA flash attention (balanced, 32 q-rows/wave) ------
__global__ __launch_bounds__(256)
void k_attn(const bf16* __restrict__ Q, const bf16* __restrict__ K,
            const bf16* __restrict__ Vt, bf16* __restrict__ O) {
    int bid = blockIdx.x;
    int p = bid & 3;
    int h = (bid >> 2) & 15;
    int b = bid >> 6;
    int tid = threadIdx.x;
    int w = tid >> 6, lane = tid & 63;
    int l16 = lane & 15, l4 = lane >> 4;
    int j = p * 4 + w;

    const bf16* qhb = Q + (size_t)(b * NH + h) * LSEQ * HD;
    int kv = h >> 1;
    const bf16* kb = K + (size_t)(b * NKV + kv) * LSEQ * HD;
    const bf16* vtb = Vt + (size_t)(b * NKV + kv) * HD * LSEQ;

    __shared__ bf16 Pl[4][32][72];

    f32x4 zero = {0.f, 0.f, 0.f, 0.f};

#pragma unroll 1
    for (int half = 0; half < 2; ++half) {
        int rowblk = half ? (31 - j) : j;
        int q0 = rowblk * 32;
        int kend = q0 + 32;

        bf16x8 qf[2][4];
#pragma unroll
        for (int rf = 0; rf < 2; ++rf)
#pragma unroll
            for (int c = 0; c < 4; ++c)
                qf[rf][c] = ld16(qhb + (size_t)(q0 + rf * 16 + l16) * HD + c * 32 + l4 * 8);

        f32x4 oacc[2][8];
#pragma unroll
        for (int rf = 0; rf < 2; ++rf)
#pragma unroll
            for (int d = 0; d < 8; ++d) oacc[rf][d] = zero;
        float mr[2][4], lr[2][4];
#pragma unroll
        for (int rf = 0; rf < 2; ++rf)
#pragma unroll
            for (int r = 0; r < 4; ++r) { mr[rf][r] = -INFINITY; lr[rf][r] = 0.f; }

        for (int kt = 0; kt < kend; kt += 64) {
            f32x4 s[2][4];
#pragma unroll
            for (int rf = 0; rf < 2; ++rf)
#pragma unroll
                for (int kf = 0; kf < 4; ++kf) s[rf][kf] = zero;
#pragma unroll
            for (int c = 0; c < 4; ++c) {
                bf16x8 kf4[4];
#pragma unroll
                for (int kf = 0; kf < 4; ++kf)
                    kf4[kf] = ld16(kb + (size_t)(kt + kf * 16 + l16) * HD + c * 32 + l4 * 8);
#pragma unroll
                for (int rf = 0; rf < 2; ++rf)
#pragma unroll
                    for (int kf = 0; kf < 4; ++kf)
                        s[rf][kf] = __builtin_amdgcn_mfma_f32_16x16x32_bf16(qf[rf][c], kf4[kf], s[rf][kf], 0, 0, 0);
            }
#pragma unroll
            for (int rf = 0; rf < 2; ++rf) {
#pragma unroll
                for (int r = 0; r < 4; ++r) {
                    int qrow = q0 + rf * 16 + l4 * 4 + r;
                    float sc[4];
                    float rm = -1e30f;
#pragma unroll
                    for (int kf = 0; kf < 4; ++kf) {
                        int key = kt + kf * 16 + l16;
                        sc[kf] = (key <= qrow) ? s[rf][kf][r] * SCALE : -1e30f;
                        rm = fmaxf(rm, sc[kf]);
                    }
#pragma unroll
                    for (int msk = 1; msk < 16; msk <<= 1) rm = fmaxf(rm, __shfl_xor(rm, msk));
                    float mn = fmaxf(mr[rf][r], rm);
                    float corr = __expf(mr[rf][r] - mn);
                    mr[rf][r] = mn;
                    float rsum = 0.f;
#pragma unroll
                    for (int kf = 0; kf < 4; ++kf) {
                        float pv = __expf(sc[kf] - mn);
                        rsum += pv;
                        Pl[w][rf * 16 + l4 * 4 + r][kf * 16 + l16] = f2b(pv);
                    }
#pragma unroll
                    for (int msk = 1; msk < 16; msk <<= 1) rsum += __shfl_xor(rsum, msk);
                    lr[rf][r] = lr[rf][r] * corr + rsum;
#pragma unroll
                    for (int d = 0; d < 8; ++d) oacc[rf][d][r] *= corr;
                }
            }
            bf16x8 pf[2][2];
#pragma unroll
            for (int rf = 0; rf < 2; ++rf)
#pragma unroll
                for (int ks = 0; ks < 2; ++ks)
                    pf[rf][ks] = ld16(&Pl[w][rf * 16 + l16][ks * 32 + l4 * 8]);
#pragma unroll
            for (int dt = 0; dt < 8; ++dt) {
#pragma unroll
                for (int ks = 0; ks < 2; ++ks) {
                    bf16x8 vfr = ld16(vtb + (size_t)(dt * 16 + l16) * LSEQ + kt + ks * 32 + l4 * 8);
#pragma unroll
                    for (int rf = 0; rf < 2; ++rf)
                        oacc[rf][dt] = __builtin_amdgcn_mfma_f32_16x16x32_bf16(pf[rf][ks], vfr, oacc[rf][dt], 0, 0, 0);
                }
            }
        }

#pragma unroll
        for (int rf = 0; rf < 2; ++rf)
#pragma unroll
            for (int r = 0; r < 4; ++r) lr[rf][r] = 1.0f / lr[rf][r];
        int trow = b * LSEQ + q0;
#pragma unroll
        for (int rf = 0; rf < 2; ++rf)
#pragma unroll
            for (int dt = 0; dt < 8; ++dt)
#pragma unroll
                for (int r = 0; r < 4; ++r) {
                    int t = trow + rf * 16 + l4 * 4 + r;
                    O[(size_t)t * HID + h * HD + dt * 16 + l16] = f2b(oacc[rf][dt][r] * lr[rf][r]);
                }
    }
}

// ---------------- launch -----------------------------------------------------
extern "C" void kernel_launch(void* const* d_in, const int* in_sizes, int n_in,
                              void* d_out, int out_size, void* d_ws, size_t ws_size,
                              hipStream_t stream) {
    const float* x    = (const float*)d_in[0];
    const float* cosT = (const float*)d_in[1];
    const float* sinT = (const float*)d_in[2];
    const int* und = (const int*)d_in[4];
    const int* gen = (const int*)d_in[5];
    const float* Wq_u = (const float*)d_in[6];
    const float* bq_u = (const float*)d_in[7];
    const float* Wk_u = (const float*)d_in[8];
    const float* bk_u = (const float*)d_in[9];
    const float* Wv_u = (const float*)d_in[10];
    const float* bv_u = (const float*)d_in[11];
    const float* Wo_u = (const float*)d_in[12];
    const float* Wq_g = (const float*)d_in[13];
    const float* bq_g = (const float*)d_in[14];
    const float* Wk_g = (const float*)d_in[15];
    const float* bk_g = (const float*)d_in[16];
    const float* Wv_g = (const float*)d_in[17];
    const float* bv_g = (const float*)d_in[18];
    const float* Wo_g = (const float*)d_in[19];
    const float* qn_u = (const float*)d_in[20];
    const float* kn_u = (const float*)d_in[21];
    const float* qn_g = (const float*)d_in[22];
    const float* kn_g = (const float*)d_in[23];
    float* out = (float*)d_out;

    char* ws = (char*)d_ws;
    size_t off = 0;
    auto alloc = [&](size_t bytes) -> void* {
        void* p = ws + off;
        off += (bytes + 255) & ~(size_t)255;
        return p;
    };
    bf16* xb      = (bf16*)alloc((size_t)T_TOK * HID * 2);
    bf16* Wqkv_u  = (bf16*)alloc((size_t)QKV_N * KDIM * 2);
    bf16* Wqkv_g  = (bf16*)alloc((size_t)QKV_N * KDIM * 2);
    bf16* Wob_u   = (bf16*)alloc((size_t)HID * HID * 2);
    bf16* Wob_g   = (bf16*)alloc((size_t)HID * HID * 2);
    int*  mod     = (int*)alloc((size_t)T_TOK * 4);
    bf16* qkv     = (bf16*)alloc((size_t)T_TOK * QKV_N * 2);
    bf16* Qa      = (bf16*)alloc((size_t)BATCH * NH  * LSEQ * HD * 2);
    bf16* Ka      = (bf16*)alloc((size_t)BATCH * NKV * LSEQ * HD * 2);
    bf16* Vt      = (bf16*)alloc((size_t)BATCH * NKV * HD * LSEQ * 2);
    bf16* Ob      = (bf16*)alloc((size_t)T_TOK * HID * 2);
    (void)ws_size; (void)in_sizes; (void)n_in; (void)out_size;

    // allow 128KB dynamic LDS for the GEMM kernels (idempotent, capture-safe)
    (void)hipFuncSetAttribute((const void*)k_gemm8p<0>,
                              hipFuncAttributeMaxDynamicSharedMemorySize, 131072);
    (void)hipFuncSetAttribute((const void*)k_gemm8p<1>,
                              hipFuncAttributeMaxDynamicSharedMemorySize, 131072);

    // converts
    k_f2b<<<1024, 256, 0, stream>>>(x, xb, T_TOK * HID);
    k_f2b<<<1024, 256, 0, stream>>>(Wq_u, Wqkv_u,               2048 * 2048);
    k_f2b<<<1024, 256, 0, stream>>>(Wk_u, Wqkv_u + 2048 * 2048, 1024 * 2048);
    k_f2b<<<1024, 256, 0, stream>>>(Wv_u, Wqkv_u + 3072 * 2048, 1024 * 2048);
    k_f2b<<<1024, 256, 0, stream>>>(Wq_g, Wqkv_g,               2048 * 2048);
    k_f2b<<<1024, 256, 0, stream>>>(Wk_g, Wqkv_g + 2048 * 2048, 1024 * 2048);
    k_f2b<<<1024, 256, 0, stream>>>(Wv_g, Wqkv_g + 3072 * 2048, 1024 * 2048);
    k_f2b<<<1024, 256, 0, stream>>>(Wo_u, Wob_u, 2048 * 2048);
    k_f2b<<<1024, 256, 0, stream>>>(Wo_g, Wob_g, 2048 * 2048);
    k_mod<<<16, 256, 0, stream>>>(und, gen, mod, T_TOK / 2);

    // routed QKV projections (M=4096, N=4096, K=2048; both modalities)
    k_gemm8p<0><<<dim3(16 * 16, 2), 512, 131072, stream>>>(
        xb, Wqkv_u, Wqkv_g, und, gen, bq_u, bk_u, bv_u, bq_g, bk_g, bv_g,
        qkv, nullptr);

    // RMS + RoPE (Q,K) and V transpose
    k_normrope<<<T_TOK, 256, 0, stream>>>(qkv, cosT, sinT, mod,
                                          qn_u, qn_g, kn_u, kn_g, Qa, Ka);
    k_vt<<<dim3(BATCH * NKV, LSEQ / 64, HD / 64), 256, 0, stream>>>(qkv, Vt);

    // causal GQA attention (balanced pairing: 512 uniform blocks)
    k_attn<<<BATCH * NH * 4, 256, 0, stream>>>(Qa, Ka, Vt, Ob);

    // routed output projections (M=4096, N=2048, K=2048; both modalities)
    k_gemm8p<1><<<dim3(8 * 16, 2), 512, 131072, stream>>>(
        Ob, Wob_u, Wob_g, und, gen, nullptr, nullptr, nullptr,
        nullptr, nullptr, nullptr, nullptr, out);
}

// Round 7
// 478.918 us; speedup vs baseline: 1.0577x; 1.0510x over previous
//
#include <hip/hip_runtime.h>
#include <hip/hip_bf16.h>
#include <stdint.h>
#include <math.h>

#define T_TOK 8192
#define HID   2048
#define NH    16
#define NKV   8
#define HD    128
#define LSEQ  1024
#define BATCH 8
#define QKV_N 4096
#define KDIM  2048
#define NT32  64          // K-tiles of 32 over KDIM=2048
#define SCALE 0.08838834764831845f   // 1/sqrt(128)

typedef __hip_bfloat16 bf16;
typedef __bf16 bf16x8 __attribute__((ext_vector_type(8)));
typedef float  f32x4  __attribute__((ext_vector_type(4)));

typedef const void __attribute__((address_space(1)))* gas_ptr;
typedef void       __attribute__((address_space(3)))* las_ptr;

__device__ __forceinline__ float b2f(bf16 x) { return __bfloat162float(x); }
__device__ __forceinline__ bf16  f2b(float x) { return __float2bfloat16(x); }
__device__ __forceinline__ unsigned short f2u(float x) {
    union { bf16 b; unsigned short u; } c; c.b = __float2bfloat16(x); return c.u;
}

__device__ __forceinline__ bf16x8 ld16(const void* p) {
    union { uint4 u; bf16x8 v; } c;
    c.u = *reinterpret_cast<const uint4*>(p);
    return c.v;
}

// async 16B/lane global->LDS. lds must be wave-uniform base; HW adds lane*16.
__device__ __forceinline__ void cp16(void* lds, const void* g) {
    __builtin_amdgcn_global_load_lds((gas_ptr)g, (las_ptr)lds, 16, 0, 0);
}

// inline-asm LDS reads: opaque to SIInsertWaitcnts -> no compiler vmcnt(0)
// drain against outstanding global_load_lds. Rule #18: every consumer chain
// is fenced by explicit lgkmcnt(0) + sched_barrier(0) before MFMA use.
#define DSR(dst, base, imm) \
    asm volatile("ds_read_b128 %0, %1 offset:" #imm : "=v"(dst) : "v"(base))
#define SCHEDB() __builtin_amdgcn_sched_barrier(0)
#define LGKM0()  asm volatile("s_waitcnt lgkmcnt(0)")

#define BARX() do { asm volatile("" ::: "memory"); \
                    __builtin_amdgcn_s_barrier();  \
                    asm volatile("" ::: "memory"); } while (0)

// ---------------- fp32 -> bf16 convert (grid-stride, vectorized) -------------
__global__ __launch_bounds__(256) void k_f2b(const float* __restrict__ in,
                                             bf16* __restrict__ out, int n) {
    int i = blockIdx.x * blockDim.x + threadIdx.x;
    int stride = gridDim.x * blockDim.x;
    const float4* in4 = (const float4*)in;
    ushort4* out4 = (ushort4*)out;
    int n4 = n >> 2;
    for (int j = i; j < n4; j += stride) {
        float4 v = in4[j];
        ushort4 o;
        o.x = f2u(v.x); o.y = f2u(v.y); o.z = f2u(v.z); o.w = f2u(v.w);
        out4[j] = o;
    }
}

// ---------------- modality map ----------------------------------------------
__global__ __launch_bounds__(256) void k_mod(const int* __restrict__ und,
                                             const int* __restrict__ gen,
                                             int* __restrict__ mod, int n) {
    int i = blockIdx.x * blockDim.x + threadIdx.x;
    if (i < n) { mod[und[i]] = 0; mod[gen[i]] = 1; }
}

// ---------------- routed GEMM: 256x256, BK=32, 4 LDS buffers, derived waits --
// Same LDS layout/swizzle as R6 (verified: conflicts=0, absmax pass). The K-
// loop now uses inline-asm ds_read_b128 + explicit waitcnts ONLY; compiler
// never sees an LDS read ordered against global_load_lds, so it cannot insert
// its own vmcnt(0) drain. Counted vmcnt(8) keeps 2 tiles in flight across
// barriers (T4); setprio brackets MFMA clusters (T5).
template<int EPI>
__global__ __launch_bounds__(512)
void k_gemm8p(const bf16* __restrict__ A,
              const bf16* __restrict__ Bw_u, const bf16* __restrict__ Bw_g,
              const int* __restrict__ und, const int* __restrict__ gen,
              const float* __restrict__ bq_u, const float* __restrict__ bk_u,
              const float* __restrict__ bv_u,
              const float* __restrict__ bq_g, const float* __restrict__ bk_g,
              const float* __restrict__ bv_g,
              bf16* __restrict__ outB, float* __restrict__ outF) {
    extern __shared__ char smem[];

    int modg = blockIdx.y;
    const bf16* Bw = modg ? Bw_g : Bw_u;
    const int* idx = modg ? gen : und;
    const float* bq = modg ? bq_g : bq_u;
    const float* bk = modg ? bk_g : bk_u;
    const float* bv = modg ? bv_g : bv_u;

    // XCD swizzle (gridDim.x % 8 == 0); tm fastest within XCD chunk
    int gx = gridDim.x;
    int bid = blockIdx.x;
    int sw = (bid & 7) * (gx >> 3) + (bid >> 3);
    int tn = sw >> 4, tm = sw & 15;

    int tid = threadIdx.x;
    int w = tid >> 6, lane = tid & 63;
    int l16 = lane & 15, l4 = lane >> 4;
    int wm = w >> 2, wn = w & 3;   // 2M x 4N waves -> per-wave C = 128 x 64

    // staging: LDS rows (j*8+w)*16 + (lane>>2), pos chunk lane&3;
    // content chunk = pos ^ ((row>>1)&3) -> source chunk = (lane&3)^((lane>>3)&3)
    int chunk = (lane & 3) ^ ((lane >> 3) & 3);
    const bf16* pS[2][2];
#pragma unroll
    for (int j = 0; j < 2; ++j) {
        int R = (j * 8 + w) * 16 + (lane >> 2);   // 0..255
        pS[0][j] = A + (size_t)idx[tm * 256 + R] * KDIM + chunk * 8;
        pS[1][j] = Bw + (size_t)(tn * 256 + R) * KDIM + chunk * 8;
    }

    auto STAGE = [&](int t, int u) {
        char* base = smem + (t & 3) * 32768 + u * 16384 + w * 1024;
        cp16(base,        pS[u][0] + t * 32);
        cp16(base + 8192, pS[u][1] + t * 32);
    };

    f32x4 acc[8][4];
#pragma unroll
    for (int m = 0; m < 8; ++m)
#pragma unroll
        for (int n = 0; n < 4; ++n) acc[m][n] = {0.f, 0.f, 0.f, 0.f};

    // prologue: 3 tiles in flight; tile 0 resident after vmcnt(8)
    STAGE(0, 0); STAGE(0, 1);
    STAGE(1, 0); STAGE(1, 1);
    STAGE(2, 0); STAGE(2, 1);
    SCHEDB();
    asm volatile("s_waitcnt vmcnt(8)");
    __builtin_amdgcn_s_barrier();

    // per-thread LDS byte offsets (loop-invariant)
    uint32_t cByte = (uint32_t)((l4 ^ ((l16 >> 1) & 3)) << 4);   // conflict-free
    uint32_t aOff = (uint32_t)(wm * 128 + l16) * 64 + cByte;            // + m*1024
    uint32_t bOff = 16384u + (uint32_t)(wn * 64 + l16) * 64 + cByte;    // + n*1024

#pragma unroll 1
    for (int t = 0; t < NT32; ++t) {
        uint32_t toff = (uint32_t)(t & 3) << 15;
        las_ptr aB = (las_ptr)(smem + toff + aOff);
        las_ptr bB = (las_ptr)(smem + toff + bOff);

        // ---------- phase 0: read B n0-3 + A m0-3; stage A(t+3)
        bf16x8 b0, b1, b2, b3, a0, a1, a2, a3;
        DSR(b0, bB, 0);    DSR(b1, bB, 1024);
        DSR(b2, bB, 2048); DSR(b3, bB, 3072);
        DSR(a0, aB, 0);    DSR(a1, aB, 1024);
        DSR(a2, aB, 2048); DSR(a3, aB, 3072);
        if (t + 3 < NT32) STAGE(t + 3, 0);
        SCHEDB();
        __builtin_amdgcn_s_barrier();
        LGKM0();
        SCHEDB();
        __builtin_amdgcn_s_setprio(1);
        acc[0][0] = __builtin_amdgcn_mfma_f32_16x16x32_bf16(a0, b0, acc[0][0], 0, 0, 0);
        acc[0][1] = __builtin_amdgcn_mfma_f32_16x16x32_bf16(a0, b1, acc[0][1], 0, 0, 0);
        acc[0][2] = __builtin_amdgcn_mfma_f32_16x16x32_bf16(a0, b2, acc[0][2], 0, 0, 0);
        acc[0][3] = __builtin_amdgcn_mfma_f32_16x16x32_bf16(a0, b3, acc[0][3], 0, 0, 0);
        acc[1][0] = __builtin_amdgcn_mfma_f32_16x16x32_bf16(a1, b0, acc[1][0], 0, 0, 0);
        acc[1][1] = __builtin_amdgcn_mfma_f32_16x16x32_bf16(a1, b1, acc[1][1], 0, 0, 0);
        acc[1][2] = __builtin_amdgcn_mfma_f32_16x16x32_bf16(a1, b2, acc[1][2], 0, 0, 0);
        acc[1][3] = __builtin_amdgcn_mfma_f32_16x16x32_bf16(a1, b3, acc[1][3], 0, 0, 0);
        acc[2][0] = __builtin_amdgcn_mfma_f32_16x16x32_bf16(a2, b0, acc[2][0], 0, 0, 0);
        acc[2][1] = __builtin_amdgcn_mfma_f32_16x16x32_bf16(a2, b1, acc[2][1], 0, 0, 0);
        acc[2][2] = __builtin_amdgcn_mfma_f32_16x16x32_bf16(a2, b2, acc[2][2], 0, 0, 0);
        acc[2][3] = __builtin_amdgcn_mfma_f32_16x16x32_bf16(a2, b3, acc[2][3], 0, 0, 0);
        acc[3][0] = __builtin_amdgcn_mfma_f32_16x16x32_bf16(a3, b0, acc[3][0], 0, 0, 0);
        acc[3][1] = __builtin_amdgcn_mfma_f32_16x16x32_bf16(a3, b1, acc[3][1], 0, 0, 0);
        acc[3][2] = __builtin_amdgcn_mfma_f32_16x16x32_bf16(a3, b2, acc[3][2], 0, 0, 0);
        acc[3][3] = __builtin_amdgcn_mfma_f32_16x16x32_bf16(a3, b3, acc[3][3], 0, 0, 0);
        __builtin_amdgcn_s_setprio(0);
        SCHEDB();
        __builtin_amdgcn_s_barrier();

        // ---------- phase 1: read A m4-7; stage B(t+3); counted vmcnt
        bf16x8 a4, a5, a6, a7;
        DSR(a4, aB, 4096); DSR(a5, aB, 5120);
        DSR(a6, aB, 6144); DSR(a7, aB, 7168);
        if (t + 3 < NT32) {
            STAGE(t + 3, 1);
            SCHEDB();
            asm volatile("s_waitcnt vmcnt(8)");   // tile t+1 resident
        } else if (t + 2 < NT32) {
            SCHEDB();
            asm volatile("s_waitcnt vmcnt(4)");
        } else {
            SCHEDB();
            asm volatile("s_waitcnt vmcnt(0)");
        }
        __builtin_amdgcn_s_barrier();
        LGKM0();
        SCHEDB();
        __builtin_amdgcn_s_setprio(1);
        acc[4][0] = __builtin_amdgcn_mfma_f32_16x16x32_bf16(a4, b0, acc[4][0], 0, 0, 0);
        acc[4][1] = __builtin_amdgcn_mfma_f32_16x16x32_bf16(a4, b1, acc[4][1], 0, 0, 0);
        acc[4][2] = __builtin_amdgcn_mfma_f32_16x16x32_bf16(a4, b2, acc[4][2], 0, 0, 0);
        acc[4][3] = __builtin_amdgcn_mfma_f32_16x16x32_bf16(a4, b3, acc[4][3], 0, 0, 0);
        acc[5][0] = __builtin_amdgcn_mfma_f32_16x16x32_bf16(a5, b0, acc[5][0], 0, 0, 0);
        acc[5][1] = __builtin_amdgcn_mfma_f32_16x16x32_bf16(a5, b1, acc[5][1], 0, 0, 0);
        acc[5][2] = __builtin_amdgcn_mfma_f32_16x16x32_bf16(a5, b2, acc[5][2], 0, 0, 0);
        acc[5][3] = __builtin_amdgcn_mfma_f32_16x16x32_bf16(a5, b3, acc[5][3], 0, 0, 0);
        acc[6][0] = __builtin_amdgcn_mfma_f32_16x16x32_bf16(a6, b0, acc[6][0], 0, 0, 0);
        acc[6][1] = __builtin_amdgcn_mfma_f32_16x16x32_bf16(a6, b1, acc[6][1], 0, 0, 0);
        acc[6][2] = __builtin_amdgcn_mfma_f32_16x16x32_bf16(a6, b2, acc[6][2], 0, 0, 0);
        acc[6][3] = __builtin_amdgcn_mfma_f32_16x16x32_bf16(a6, b3, acc[6][3], 0, 0, 0);
        acc[7][0] = __builtin_amdgcn_mfma_f32_16x16x32_bf16(a7, b0, acc[7][0], 0, 0, 0);
        acc[7][1] = __builtin_amdgcn_mfma_f32_16x16x32_bf16(a7, b1, acc[7][1], 0, 0, 0);
        acc[7][2] = __builtin_amdgcn_mfma_f32_16x16x32_bf16(a7, b2, acc[7][2], 0, 0, 0);
        acc[7][3] = __builtin_amdgcn_mfma_f32_16x16x32_bf16(a7, b3, acc[7][3], 0, 0, 0);
        __builtin_amdgcn_s_setprio(0);
        SCHEDB();
        __builtin_amdgcn_s_barrier();
    }

    int rowbase = tm * 256 + wm * 128;
    int colbase = tn * 256 + wn * 64;
#pragma unroll
    for (int m = 0; m < 8; ++m) {
#pragma unroll
        for (int r = 0; r < 4; ++r) {
            int row = rowbase + m * 16 + l4 * 4 + r;
            int token = idx[row];
#pragma unroll
            for (int n = 0; n < 4; ++n) {
                int col = colbase + n * 16 + l16;
                float v = acc[m][n][r];
                if (EPI == 0) {
                    float bias = (col < 2048) ? bq[col]
                               : (col < 3072) ? bk[col - 2048] : bv[col - 3072];
                    outB[(size_t)token * QKV_N + col] = f2b(v + bias);
                } else {
                    outF[(size_t)token * HID + col] = v;
                }
            }
        }
    }
}

// ---------------- per-head RMSNorm + RoPE (Q,K only) -------------------------
__global__ __launch_bounds__(256)
void k_normrope(const bf16* __restrict__ qkv,
                const float* __restrict__ cosT, const float* __restrict__ sinT,
                const int* __restrict__ mod,
                const float* __restrict__ qn_u, const float* __restrict__ qn_g,
                const float* __restrict__ kn_u, const float* __restrict__ kn_g,
                bf16* __restrict__ Qo, bf16* __restrict__ Ko) {
    int t = blockIdx.x;
    int tid = threadIdx.x;
    int w = tid >> 6, lane = tid & 63;
    int m = mod[t];
    int b = t >> 10, pos = t & 1023;
    const bf16* row = qkv + (size_t)t * QKV_N;
    int d0 = 2 * lane, d1 = 2 * lane + 1;
    float c0 = cosT[(size_t)t * HD + d0], c1 = cosT[(size_t)t * HD + d1];
    float s0 = sinT[(size_t)t * HD + d0], s1 = sinT[(size_t)t * HD + d1];
    float sgn = (lane < 32) ? -1.f : 1.f;
    const float* qw = m ? qn_g : qn_u;
    const float* kw = m ? kn_g : kn_u;

    for (int u = w; u < 24; u += 4) {
        float v0 = b2f(row[u * HD + d0]);
        float v1 = b2f(row[u * HD + d1]);
        float ss = v0 * v0 + v1 * v1;
#pragma unroll
        for (int msk = 1; msk < 64; msk <<= 1) ss += __shfl_xor(ss, msk);
        float rs = rsqrtf(ss * (1.0f / HD) + 1e-6f);
        const float* wsc = (u < 16) ? qw : kw;
        float n0 = v0 * rs * wsc[d0], n1 = v1 * rs * wsc[d1];
        float o0 = __shfl_xor(n0, 32), o1 = __shfl_xor(n1, 32);
        float r0 = n0 * c0 + sgn * o0 * s0;
        float r1 = n1 * c1 + sgn * o1 * s1;
        if (u < 16) {
            size_t o = ((size_t)(b * NH + u) * LSEQ + pos) * HD;
            Qo[o + d0] = f2b(r0); Qo[o + d1] = f2b(r1);
        } else {
            size_t o = ((size_t)(b * NKV + (u - 16)) * LSEQ + pos) * HD;
            Ko[o + d0] = f2b(r0); Ko[o + d1] = f2b(r1);
        }
    }
}

// ---------------- V transpose: qkv[t][3072+kv*128+d] -> Vt[b,kv][d][pos] -----
__global__ __launch_bounds__(256)
void k_vt(const bf16* __restrict__ qkv, bf16* __restrict__ Vt) {
    __shared__ bf16 lds[64][72];
    int bk = blockIdx.x;
    int b = bk >> 3, kv = bk & 7;
    int pos0 = blockIdx.y * 64;
    int d0 = blockIdx.z * 64;
    int tid = threadIdx.x;

#pragma unroll
    for (int it = 0; it < 2; ++it) {
        int c = tid + it * 256;
        int row = c >> 3, col8 = (c & 7) * 8;
        const bf16* src = qkv + (size_t)(b * LSEQ + pos0 + row) * QKV_N
                        + 3072 + kv * HD + d0 + col8;
        *reinterpret_cast<uint4*>(&lds[row][col8]) = *reinterpret_cast<const uint4*>(src);
    }
    __syncthreads();

#pragma unroll
    for (int it = 0; it < 2; ++it) {
        int c = tid + it * 256;
        int drow = c & 63, pos8 = (c >> 6) * 8;
        union { unsigned short s[8]; uint4 u; } g;
#pragma unroll
        for (int j = 0; j < 8; ++j)
            g.s[j] = *reinterpret_cast<const unsigned short*>(&lds[pos8 + j][drow]);
        bf16* dst = Vt + ((size_t)bk * HD + d0 + drow) * LSEQ + pos0 + pos8;
        *reinterpret_cast<uint4*>(dst) = g.u;
    }
}

// ---------------- causal GQA flash attention (balanced, 32 q-rows/wave) ------
__global__ __launch_bounds__(256)
void k_attn(const bf16* __restrict__ Q, const bf16* __restrict__ K,
            const bf16* __restrict__ Vt, bf16* __restrict__ O) {
    int bid = blockIdx.x;
    int p = bid & 3;
    int h = (bid >> 2) & 15;
    int b = bid >> 6;
    int tid = threadIdx.x;
    int w = tid >> 6, lane = tid & 63;
    int l16 = lane & 15, l4 = lane >> 4;
    int j = p * 4 + w;

    const bf16* qhb = Q + (size_t)(b * NH + h) * LSEQ * HD;
    int kv = h >> 1;
    const bf16* kb = K + (size_t)(b * NKV + kv) * LSEQ * HD;
    const bf16* vtb = Vt + (size_t)(b * NKV + kv) * HD * LSEQ;

    __shared__ bf16 Pl[4][32][72];

    f32x4 zero = {0.f, 0.f, 0.f, 0.f};

#pragma unroll 1
    for (int half = 0; half < 2; ++half) {
        int rowblk = half ? (31 - j) : j;
        int q0 = rowblk * 32;
        int kend = q0 + 32;

        bf16x8 qf[2][4];
#pragma unroll
        for (int rf = 0; rf < 2; ++rf)
#pragma unroll
            for (int c = 0; c < 4; ++c)
                qf[rf][c] = ld16(qhb + (size_t)(q0 + rf * 16 + l16) * HD + c * 32 + l4 * 8);

        f32x4 oacc[2][8];
#pragma unroll
        for (int rf = 0; rf < 2; ++rf)
#pragma unroll
            for (int d = 0; d < 8; ++d) oacc[rf][d] = zero;
        float mr[2][4], lr[2][4];
#pragma unroll
        for (int rf = 0; rf < 2; ++rf)
#pragma unroll
            for (int r = 0; r < 4; ++r) { mr[rf][r] = -INFINITY; lr[rf][r] = 0.f; }

        for (int kt = 0; kt < kend; kt += 64) {
            f32x4 s[2][4];
#pragma unroll
            for (int rf = 0; rf < 2; ++rf)
#pragma unroll
                for (int kf = 0; kf < 4; ++kf) s[rf][kf] = zero;
#pragma unroll
            for (int c = 0; c < 4; ++c) {
                bf16x8 kf4[4];
#pragma unroll
                for (int kf = 0; kf < 4; ++kf)
                    kf4[kf] = ld16(kb + (size_t)(kt + kf * 16 + l16) * HD + c * 32 + l4 * 8);
#pragma unroll
                for (int rf = 0; rf < 2; ++rf)
#pragma unroll
                    for (int kf = 0; kf < 4; ++kf)
                        s[rf][kf] = __builtin_amdgcn_mfma_f32_16x16x32_bf16(qf[rf][c], kf4[kf], s[rf][kf], 0, 0, 0);
            }
#pragma unroll
            for (int rf = 0; rf < 2; ++rf) {
#pragma unroll
                for (int r = 0; r < 4; ++r) {
                    int qrow = q0 + rf * 16 + l4 * 4 + r;
                    float sc[4];
                    float rm = -1e30f;
#pragma unroll
                    for (int kf = 0; kf < 4; ++kf) {
                        int key = kt + kf * 16 + l16;
                        sc[kf] = (key <= qrow) ? s[rf][kf][r] * SCALE : -1e30f;
                        rm = fmaxf(rm, sc[kf]);
                    }
#pragma unroll
                    for (int msk = 1; msk < 16; msk <<= 1) rm = fmaxf(rm, __shfl_xor(rm, msk));
                    float mn = fmaxf(mr[rf][r], rm);
                    float corr = __expf(mr[rf][r] - mn);
                    mr[rf][r] = mn;
                    float rsum = 0.f;
#pragma unroll
                    for (int kf = 0; kf < 4; ++kf) {
                        float pv = __expf(sc[kf] - mn);
                        rsum += pv;
                        Pl[w][rf * 16 + l4 * 4 + r][kf * 16 + l16] = f2b(pv);
                    }
#pragma unroll
                    for (int msk = 1; msk < 16; msk <<= 1) rsum += __shfl_xor(rsum, msk);
                    lr[rf][r] = lr[rf][r] * corr + rsum;
#pragma unroll
                    for (int d = 0; d < 8; ++d) oacc[rf][d][r] *= corr;
                }
            }
            bf16x8 pf[2][2];
#pragma unroll
            for (int rf = 0; rf < 2; ++rf)
#pragma unroll
                for (int ks = 0; ks < 2; ++ks)
                    pf[rf][ks] = ld16(&Pl[w][rf * 16 + l16][ks * 32 + l4 * 8]);
#pragma unroll
            for (int dt = 0; dt < 8; ++dt) {
#pragma unroll
                for (int ks = 0; ks < 2; ++ks) {
                    bf16x8 vfr = ld16(vtb + (size_t)(dt * 16 + l16) * LSEQ + kt + ks * 32 + l4 * 8);
#pragma unroll
                    for (int rf = 0; rf < 2; ++rf)
                        oacc[rf][dt] = __builtin_amdgcn_mfma_f32_16x16x32_bf16(pf[rf][ks], vfr, oacc[rf][dt], 0, 0, 0);
                }
            }
        }

#pragma unroll
        for (int rf = 0; rf < 2; ++rf)
#pragma unroll
            for (int r = 0; r < 4; ++r) lr[rf][r] = 1.0f / lr[rf][r];
        int trow = b * LSEQ + q0;
#pragma unroll
        for (int rf = 0; rf < 2; ++rf)
#pragma unroll
            for (int dt = 0; dt < 8; ++dt)
#pragma unroll
                for (int r = 0; r < 4; ++r) {
                    int t = trow + rf * 16 + l4 * 4 + r;
                    O[(size_t)t * HID + h * HD + dt * 16 + l16] = f2b(oacc[rf][dt][r] * lr[rf][r]);
                }
    }
}

// ---------------- launch -----------------------------------------------------
extern "C" void kernel_launch(void* const* d_in, const int* in_sizes, int n_in,
                              void* d_out, int out_size, void* d_ws, size_t ws_size,
                              hipStream_t stream) {
    const float* x    = (const float*)d_in[0];
    const float* cosT = (const float*)d_in[1];
    const float* sinT = (const float*)d_in[2];
    const int* und = (const int*)d_in[4];
    const int* gen = (const int*)d_in[5];
    const float* Wq_u = (const float*)d_in[6];
    const float* bq_u = (const float*)d_in[7];
    const float* Wk_u = (const float*)d_in[8];
    const float* bk_u = (const float*)d_in[9];
    const float* Wv_u = (const float*)d_in[10];
    const float* bv_u = (const float*)d_in[11];
    const float* Wo_u = (const float*)d_in[12];
    const float* Wq_g = (const float*)d_in[13];
    const float* bq_g = (const float*)d_in[14];
    const float* Wk_g = (const float*)d_in[15];
    const float* bk_g = (const float*)d_in[16];
    const float* Wv_g = (const float*)d_in[17];
    const float* bv_g = (const float*)d_in[18];
    const float* Wo_g = (const float*)d_in[19];
    const float* qn_u = (const float*)d_in[20];
    const float* kn_u = (const float*)d_in[21];
    const float* qn_g = (const float*)d_in[22];
    const float* kn_g = (const float*)d_in[23];
    float* out = (float*)d_out;

    char* ws = (char*)d_ws;
    size_t off = 0;
    auto alloc = [&](size_t bytes) -> void* {
        void* p = ws + off;
        off += (bytes + 255) & ~(size_t)255;
        return p;
    };
    bf16* xb      = (bf16*)alloc((size_t)T_TOK * HID * 2);
    bf16* Wqkv_u  = (bf16*)alloc((size_t)QKV_N * KDIM * 2);
    bf16* Wqkv_g  = (bf16*)alloc((size_t)QKV_N * KDIM * 2);
    bf16* Wob_u   = (bf16*)alloc((size_t)HID * HID * 2);
    bf16* Wob_g   = (bf16*)alloc((size_t)HID * HID * 2);
    int*  mod     = (int*)alloc((size_t)T_TOK * 4);
    bf16* qkv     = (bf16*)alloc((size_t)T_TOK * QKV_N * 2);
    bf16* Qa      = (bf16*)alloc((size_t)BATCH * NH  * LSEQ * HD * 2);
    bf16* Ka      = (bf16*)alloc((size_t)BATCH * NKV * LSEQ * HD * 2);
    bf16* Vt      = (bf16*)alloc((size_t)BATCH * NKV * HD * LSEQ * 2);
    bf16* Ob      = (bf16*)alloc((size_t)T_TOK * HID * 2);
    (void)ws_size; (void)in_sizes; (void)n_in; (void)out_size;

    // allow 128KB dynamic LDS for the GEMM kernels (idempotent, capture-safe)
    (void)hipFuncSetAttribute((const void*)k_gemm8p<0>,
                              hipFuncAttributeMaxDynamicSharedMemorySize, 131072);
    (void)hipFuncSetAttribute((const void*)k_gemm8p<1>,
                              hipFuncAttributeMaxDynamicSharedMemorySize, 131072);

    // converts
    k_f2b<<<1024, 256, 0, stream>>>(x, xb, T_TOK * HID);
    k_f2b<<<1024, 256, 0, stream>>>(Wq_u, Wqkv_u,               2048 * 2048);
    k_f2b<<<1024, 256, 0, stream>>>(Wk_u, Wqkv_u + 2048 * 2048, 1024 * 2048);
    k_f2b<<<1024, 256, 0, stream>>>(Wv_u, Wqkv_u + 3072 * 2048, 1024 * 2048);
    k_f2b<<<1024, 256, 0, stream>>>(Wq_g, Wqkv_g,               2048 * 2048);
    k_f2b<<<1024, 256, 0, stream>>>(Wk_g, Wqkv_g + 2048 * 2048, 1024 * 2048);
    k_f2b<<<1024, 256, 0, stream>>>(Wv_g, Wqkv_g + 3072 * 2048, 1024 * 2048);
    k_f2b<<<1024, 256, 0, stream>>>(Wo_u, Wob_u, 2048 * 2048);
    k_f2b<<<1024, 256, 0, stream>>>(Wo_g, Wob_g, 2048 * 2048);
    k_mod<<<16, 256, 0, stream>>>(und, gen, mod, T_TOK / 2);

    // routed QKV projections (M=4096, N=4096, K=2048; both modalities)
    k_gemm8p<0><<<dim3(16 * 16, 2), 512, 131072, stream>>>(
        xb, Wqkv_u, Wqkv_g, und, gen, bq_u, bk_u, bv_u, bq_g, bk_g, bv_g,
        qkv, nullptr);

    // RMS + RoPE (Q,K) and V transpose
    k_normrope<<<T_TOK, 256, 0, stream>>>(qkv, cosT, sinT, mod,
                                          qn_u, qn_g, kn_u, kn_g, Qa, Ka);
    k_vt<<<dim3(BATCH * NKV, LSEQ / 64, HD / 64), 256, 0, stream>>>(qkv, Vt);

    // causal GQA attention (balanced pairing: 512 uniform blocks)
    k_attn<<<BATCH * NH * 4, 256, 0, stream>>>(Qa, Ka, Vt, Ob);

    // routed output projections (M=4096, N=2048, K=2048; both modalities)
    k_gemm8p<1><<<dim3(8 * 16, 2), 512, 131072, stream>>>(
        Ob, Wob_u, Wob_g, und, gen, nullptr, nullptr, nullptr,
        nullptr, nullptr, nullptr, nullptr, out);
}